// Round 4
// baseline (246.575 us; speedup 1.0000x reference)
//
#include <hip/hip_runtime.h>

#define TOPK 10
#define CLIP 0.05f
#define EPSV 1e-8f
#define ALPHA1 2.0f
#define ALPHA_OTHER 0.5f
#define TCAND 2.5f     // candidate threshold; guarded by exact fallback in fix_kernel
#define MAXC 128       // per-row candidate capacity (mean ~60, sd ~8 at TCAND=2.5)

// sortable packed key: (monotone float key << 32) | (C - col)
// larger packed = larger value; on equal value, smaller col wins (matches lax.top_k)
__device__ __forceinline__ unsigned long long pack_vc(float v, int c, int C) {
  unsigned u = __float_as_uint(v);
  unsigned key = (u & 0x80000000u) ? ~u : (u | 0x80000000u);
  return ((unsigned long long)key << 32) | (unsigned)(C - c);
}
__device__ __forceinline__ float unpack_v(unsigned long long p) {
  unsigned key = (unsigned)(p >> 32);
  unsigned u = (key & 0x80000000u) ? (key & 0x7fffffffu) : ~key;
  return __uint_as_float(u);
}
__device__ __forceinline__ int unpack_c(unsigned long long p, int C) {
  return C - (int)(unsigned)(p & 0xffffffffu);
}

// base * w for one element. pos = (y == 1). Fast rcp avoids the full div sequence.
__device__ __forceinline__ float base_w(float xv, bool pos) {
  float e = __expf(-xv);
  float p = __builtin_amdgcn_rcpf(1.f + e);      // sigmoid
  float xneg = fminf(1.f - p + CLIP, 1.f);
  float q = pos ? p : xneg;
  float b = __logf(fmaxf(q, EPSV));
  float t = 1.f - q;                             // 1 - pt
  float t2 = t * t;
  float w = pos ? t : t2 * t2;                   // gamma: pos=1, neg=4
  return b * w;
}

__device__ __forceinline__ void push_cand(float v, long flat, int C, double invC,
                                          int* __restrict__ cnt,
                                          unsigned long long* __restrict__ cand,
                                          int maxc) {
  int row = (int)((double)flat * invC);
  int col = (int)(flat - (long)row * (long)C);
  if (col >= C) { row++; col -= C; }
  if (col < 0)  { row--; col += C; }
  int i = atomicAdd(&cnt[row], 1);
  if (i < maxc) cand[(long)row * maxc + i] = pack_vc(v, col, C);
}

__device__ __forceinline__ void k1proc(float4 X, float4 Y, float4& acc, long flat,
                                       int C, double invC, int* __restrict__ cnt,
                                       unsigned long long* __restrict__ cand,
                                       int maxc) {
  acc.x += base_w(X.x, Y.x > 0.5f);
  acc.y += base_w(X.y, Y.y > 0.5f);
  acc.z += base_w(X.z, Y.z > 0.5f);
  acc.w += base_w(X.w, Y.w > 0.5f);
  float mx = fmaxf(fmaxf(X.x, X.y), fmaxf(X.z, X.w));
  if (mx > TCAND) {
    if (X.x > TCAND) push_cand(X.x, flat + 0, C, invC, cnt, cand, maxc);
    if (X.y > TCAND) push_cand(X.y, flat + 1, C, invC, cnt, cand, maxc);
    if (X.z > TCAND) push_cand(X.z, flat + 2, C, invC, cnt, cand, maxc);
    if (X.w > TCAND) push_cand(X.w, flat + 3, C, invC, cnt, cand, maxc);
  }
}

// Kernel 1: pure flat stream — sum of base*w over all B*C elements + candidate filter.
__global__ __launch_bounds__(256) void stream_kernel(
    const float* __restrict__ x, const float* __restrict__ y,
    float* __restrict__ out, int* __restrict__ cnt,
    unsigned long long* __restrict__ cand, long N, int C, double invC, int maxc)
{
  const long N4 = N >> 2;
  const long S = (long)gridDim.x * 256;
  const long gtid = (long)blockIdx.x * 256 + threadIdx.x;
  const float4* __restrict__ x4 = (const float4*)x;
  const float4* __restrict__ y4 = (const float4*)y;

  float4 a0 = make_float4(0.f, 0.f, 0.f, 0.f);
  float4 a1 = make_float4(0.f, 0.f, 0.f, 0.f);
  float4 a2 = make_float4(0.f, 0.f, 0.f, 0.f);
  float4 a3 = make_float4(0.f, 0.f, 0.f, 0.f);

  long i = gtid;
  // main loop: 8 unconditional loads issued together (4 x4 + 4 y4)
  for (; i + 3 * S < N4; i += 4 * S) {
    float4 X0 = x4[i];         float4 Y0 = y4[i];
    float4 X1 = x4[i + S];     float4 Y1 = y4[i + S];
    float4 X2 = x4[i + 2 * S]; float4 Y2 = y4[i + 2 * S];
    float4 X3 = x4[i + 3 * S]; float4 Y3 = y4[i + 3 * S];
    k1proc(X0, Y0, a0, 4 * i,           C, invC, cnt, cand, maxc);
    k1proc(X1, Y1, a1, 4 * (i + S),     C, invC, cnt, cand, maxc);
    k1proc(X2, Y2, a2, 4 * (i + 2 * S), C, invC, cnt, cand, maxc);
    k1proc(X3, Y3, a3, 4 * (i + 3 * S), C, invC, cnt, cand, maxc);
  }
  for (; i < N4; i += S) {
    float4 X = x4[i]; float4 Y = y4[i];
    k1proc(X, Y, a0, 4 * i, C, invC, cnt, cand, maxc);
  }
  float sum = (a0.x + a0.y + a0.z + a0.w) + (a1.x + a1.y + a1.z + a1.w)
            + (a2.x + a2.y + a2.z + a2.w) + (a3.x + a3.y + a3.z + a3.w);
  // scalar remainder (N % 4), handled by one thread
  if (gtid == 0) {
    for (long j = N4 * 4; j < N; j++) {
      float xv = x[j];
      sum += base_w(xv, y[j] > 0.5f);
      if (xv > TCAND) push_cand(xv, j, C, invC, cnt, cand, maxc);
    }
  }

  // block reduce -> one atomic
#pragma unroll
  for (int off = 32; off > 0; off >>= 1) sum += __shfl_xor(sum, off, 64);
  __shared__ float s_sum[4];
  const int lane = threadIdx.x & 63, wave = threadIdx.x >> 6;
  if (lane == 0) s_sum[wave] = sum;
  __syncthreads();
  if (threadIdx.x == 0)
    atomicAdd(out, -(s_sum[0] + s_sum[1] + s_sum[2] + s_sum[3]));
}

// Kernel 2: per-row top-10 + whitelist fixup. One block per row.
__global__ __launch_bounds__(256) void fix_kernel(
    const float* __restrict__ x, const float* __restrict__ y,
    const int* __restrict__ compost, const int* __restrict__ recycle,
    const int* __restrict__ donate, const int* __restrict__ wl_map,
    float* __restrict__ out, const int* __restrict__ cnt,
    const unsigned long long* __restrict__ cand,
    int C, int n1, int n2, int n3, int maxc)
{
  const int row = blockIdx.x;
  const float* xr = x + (size_t)row * (size_t)C;
  const float* yr = y + (size_t)row * (size_t)C;
  const int tid = threadIdx.x;
  const int lane = tid & 63;
  const int wave = tid >> 6;

  __shared__ int s_has[3];
  __shared__ unsigned long long s_top[TOPK];

  if (tid < 3) s_has[tid] = 0;
  __syncthreads();

  // waves 1-3: whitelist presence gathers (benign write-1 races)
  const int ntot = n1 + n2 + n3;
  if (wave > 0) {
    for (int i = tid - 64; i < ntot; i += 192) {
      int which, colI;
      if (i < n1)           { which = 0; colI = compost[i]; }
      else if (i < n1 + n2) { which = 1; colI = recycle[i - n1]; }
      else                  { which = 2; colI = donate[i - n1 - n2]; }
      if (yr[colI] > 0.5f) s_has[which] = 1;
    }
  }

  // wave 0: exact top-10
  if (wave == 0) {
    const int c = cnt[row];
    unsigned long long ls[TOPK];
#pragma unroll
    for (int s = 0; s < TOPK; s++) ls[s] = 0ULL;

#define INSERT(P)                                                          \
    do {                                                                   \
      unsigned long long _p = (P);                                         \
      if (_p > ls[TOPK - 1]) {                                             \
        _Pragma("unroll")                                                  \
        for (int _s = 0; _s < TOPK; _s++) {                                \
          bool _g = _p > ls[_s];                                           \
          unsigned long long _t = _g ? ls[_s] : _p;                        \
          ls[_s] = _g ? _p : ls[_s];                                       \
          _p = _t;                                                         \
        }                                                                  \
      }                                                                    \
    } while (0)

    if (c >= TOPK && c <= maxc) {
      const unsigned long long* cr = cand + (long)row * maxc;
      for (int i = lane; i < c; i += 64) INSERT(cr[i]);
    } else {
      // exact fallback: rescan the (L3-resident) row
      for (int col = lane; col < C; col += 64) INSERT(pack_vc(xr[col], col, C));
    }
#undef INSERT

    // 10 rounds of 64-lane packed max; pop winner (packed values unique)
    for (int r = 0; r < TOPK; r++) {
      unsigned long long mine = ls[0];
      unsigned long long best = mine;
#pragma unroll
      for (int off = 32; off > 0; off >>= 1) {
        unsigned long long o = __shfl_xor(best, off, 64);
        best = (o > best) ? o : best;
      }
      if (lane == 0) s_top[r] = best;
      if (mine == best) {
#pragma unroll
        for (int s = 0; s < TOPK - 1; s++) ls[s] = ls[s + 1];
        ls[TOPK - 1] = 0ULL;
      }
    }
  }
  __syncthreads();

  if (tid == 0) {
    const bool h1 = s_has[0] != 0, h2 = s_has[1] != 0, h3 = s_has[2] != 0;
    const bool gt4 = !(h1 || h2 || h3);

    // rank-sequential multiplier logic (mirrors the lax.scan)
    bool found = false;
    float fr[TOPK];
#pragma unroll
    for (int r = 0; r < TOPK; r++) {
      int col = unpack_c(s_top[r], C);
      int wl = wl_map[col];
      bool in_map = wl > 0;
      bool in_gt = (wl == 1 && h1) || (wl == 2 && h2) ||
                   (wl == 3 && h3) || (wl == 4 && gt4);
      float f = 1.f;
      if (in_map && gt4) f *= ALPHA_OTHER;
      if (in_map && !in_gt && !found) f *= ALPHA1;
      fr[r] = f;
      found = found || (in_map && in_gt);
    }
    const float extra = found ? 1.f : ALPHA1;
    float total = 0.f;
#pragma unroll
    for (int r = 0; r < TOPK; r++) {
      float mult = fr[r] * extra;
      if (mult != 1.f) {
        int col = unpack_c(s_top[r], C);
        float xv = unpack_v(s_top[r]);
        total += (mult - 1.f) * base_w(xv, yr[col] > 0.5f);
      }
    }
    if (total != 0.f) atomicAdd(out, -total);
  }
}

extern "C" void kernel_launch(void* const* d_in, const int* in_sizes, int n_in,
                              void* d_out, int out_size, void* d_ws, size_t ws_size,
                              hipStream_t stream) {
  const float* x       = (const float*)d_in[0];
  const float* y       = (const float*)d_in[1];
  const int*   compost = (const int*)d_in[2];
  const int*   recycle = (const int*)d_in[3];
  const int*   donate  = (const int*)d_in[4];
  const int*   wl_map  = (const int*)d_in[5];
  float* out = (float*)d_out;

  const int C  = in_sizes[5];
  const int B  = in_sizes[0] / C;
  const long N = (long)in_sizes[0];
  const int n1 = in_sizes[2], n2 = in_sizes[3], n3 = in_sizes[4];

  // workspace layout: [0, B*4) row counts; then 8-aligned candidate array
  size_t cand_off = ((size_t)B * 4 + 7) & ~(size_t)7;
  int maxc = MAXC;
  if (ws_size < cand_off + (size_t)B * maxc * 8) {
    size_t fit = (ws_size > cand_off) ? (ws_size - cand_off) / ((size_t)B * 8) : 0;
    maxc = (int)fit;  // maxc < TOPK simply forces the exact fallback path
  }
  int* cnt = (int*)d_ws;
  unsigned long long* cand = (unsigned long long*)((char*)d_ws + cand_off);
  double invC = 1.0 / (double)C;

  hipMemsetAsync(out, 0, sizeof(float), stream);
  hipMemsetAsync(cnt, 0, (size_t)B * 4, stream);
  stream_kernel<<<1024, 256, 0, stream>>>(x, y, out, cnt, cand, N, C, invC, maxc);
  fix_kernel<<<B, 256, 0, stream>>>(x, y, compost, recycle, donate, wl_map,
                                    out, cnt, cand, C, n1, n2, n3, maxc);
}

// Round 5
// 242.597 us; speedup vs baseline: 1.0164x; 1.0164x over previous
//
#include <hip/hip_runtime.h>

#define TOPK 10
#define CLIP 0.05f
#define EPSV 1e-8f
#define ALPHA1 2.0f
#define ALPHA_OTHER 0.5f
#define TCAND 2.5f     // candidate threshold; guarded by exact fallback in fix_kernel
#define MAXC 128       // per-row candidate capacity (mean ~60, sd ~8 at TCAND=2.5)

// sortable packed key: (monotone float key << 32) | (C - col)
// larger packed = larger value; on equal value, smaller col wins (matches lax.top_k)
__device__ __forceinline__ unsigned long long pack_vc(float v, int c, int C) {
  unsigned u = __float_as_uint(v);
  unsigned key = (u & 0x80000000u) ? ~u : (u | 0x80000000u);
  return ((unsigned long long)key << 32) | (unsigned)(C - c);
}
__device__ __forceinline__ float unpack_v(unsigned long long p) {
  unsigned key = (unsigned)(p >> 32);
  unsigned u = (key & 0x80000000u) ? (key & 0x7fffffffu) : ~key;
  return __uint_as_float(u);
}
__device__ __forceinline__ int unpack_c(unsigned long long p, int C) {
  return C - (int)(unsigned)(p & 0xffffffffu);
}

// base * w for one element. pos = (y == 1). Fast rcp avoids the full div sequence.
__device__ __forceinline__ float base_w(float xv, bool pos) {
  float e = __expf(-xv);
  float p = __builtin_amdgcn_rcpf(1.f + e);      // sigmoid
  float xneg = fminf(1.f - p + CLIP, 1.f);
  float q = pos ? p : xneg;
  float b = __logf(fmaxf(q, EPSV));
  float t = 1.f - q;                             // 1 - pt
  float t2 = t * t;
  float w = pos ? t : t2 * t2;                   // gamma: pos=1, neg=4
  return b * w;
}

__device__ __forceinline__ void push_cand(float v, long flat, int C, double invC,
                                          int* __restrict__ cnt,
                                          unsigned long long* __restrict__ cand,
                                          int maxc) {
  int row = (int)((double)flat * invC);
  int col = (int)(flat - (long)row * (long)C);
  if (col >= C) { row++; col -= C; }
  if (col < 0)  { row--; col += C; }
  int i = atomicAdd(&cnt[row], 1);
  if (i < maxc) cand[(long)row * maxc + i] = pack_vc(v, col, C);
}

// pure (side-effect-free) 4-element step: accumulate + set 1 candidate bit
__device__ __forceinline__ void proc4(float4 X, float4 Y, float4& acc,
                                      unsigned& cmask, int slot) {
  acc.x += base_w(X.x, Y.x > 0.5f);
  acc.y += base_w(X.y, Y.y > 0.5f);
  acc.z += base_w(X.z, Y.z > 0.5f);
  acc.w += base_w(X.w, Y.w > 0.5f);
  float mx = fmaxf(fmaxf(X.x, X.y), fmaxf(X.z, X.w));
  cmask |= (mx > TCAND ? 1u : 0u) << slot;
}

// Kernel 1: pure flat stream — sum of base*w over all B*C elements.
// Candidate detection is a register bitmask (bit k <-> float4 at gtid + k*S);
// the atomics run AFTER the loop so nothing stalls the stream.
__global__ __launch_bounds__(256) void stream_kernel(
    const float* __restrict__ x, const float* __restrict__ y,
    float* __restrict__ out, int* __restrict__ cnt,
    unsigned long long* __restrict__ cand, long N, int C, double invC, int maxc)
{
  const long N4 = N >> 2;
  const long S = (long)gridDim.x * 256;
  const long gtid = (long)blockIdx.x * 256 + threadIdx.x;
  const float4* __restrict__ x4 = (const float4*)x;
  const float4* __restrict__ y4 = (const float4*)y;

  float4 a0 = make_float4(0.f, 0.f, 0.f, 0.f);
  float4 a1 = make_float4(0.f, 0.f, 0.f, 0.f);
  float4 a2 = make_float4(0.f, 0.f, 0.f, 0.f);
  float4 a3 = make_float4(0.f, 0.f, 0.f, 0.f);
  unsigned cmask = 0;

  int k = 0;
  long i = gtid;
  // main loop: 8 unconditional loads, no branches, no side effects
  for (; i + 3 * S < N4; i += 4 * S, k += 4) {
    float4 X0 = x4[i];         float4 Y0 = y4[i];
    float4 X1 = x4[i + S];     float4 Y1 = y4[i + S];
    float4 X2 = x4[i + 2 * S]; float4 Y2 = y4[i + 2 * S];
    float4 X3 = x4[i + 3 * S]; float4 Y3 = y4[i + 3 * S];
    proc4(X0, Y0, a0, cmask, k + 0);
    proc4(X1, Y1, a1, cmask, k + 1);
    proc4(X2, Y2, a2, cmask, k + 2);
    proc4(X3, Y3, a3, cmask, k + 3);
  }
  // tail: same bitmask scheme, still side-effect-free
  for (; i < N4; i += S, k++) {
    float4 X = x4[i]; float4 Y = y4[i];
    proc4(X, Y, a0, cmask, k);
  }
  float sum = (a0.x + a0.y + a0.z + a0.w) + (a1.x + a1.y + a1.z + a1.w)
            + (a2.x + a2.y + a2.z + a2.w) + (a3.x + a3.y + a3.z + a3.w);
  // scalar remainder (N % 4), handled by one thread
  if (gtid == 0) {
    for (long j = N4 * 4; j < N; j++) {
      float xv = x[j];
      sum += base_w(xv, y[j] > 0.5f);
      if (xv > TCAND) push_cand(xv, j, C, invC, cnt, cand, maxc);
    }
  }

  // materialize candidates (rare: ~0.2/thread; reload from warm cache)
  while (cmask) {
    int b = __ffs(cmask) - 1;
    cmask &= cmask - 1;
    long ii = gtid + (long)b * S;
    float4 X = x4[ii];
    long fb = 4 * ii;
    if (X.x > TCAND) push_cand(X.x, fb + 0, C, invC, cnt, cand, maxc);
    if (X.y > TCAND) push_cand(X.y, fb + 1, C, invC, cnt, cand, maxc);
    if (X.z > TCAND) push_cand(X.z, fb + 2, C, invC, cnt, cand, maxc);
    if (X.w > TCAND) push_cand(X.w, fb + 3, C, invC, cnt, cand, maxc);
  }

  // block reduce -> one atomic
#pragma unroll
  for (int off = 32; off > 0; off >>= 1) sum += __shfl_xor(sum, off, 64);
  __shared__ float s_sum[4];
  const int lane = threadIdx.x & 63, wave = threadIdx.x >> 6;
  if (lane == 0) s_sum[wave] = sum;
  __syncthreads();
  if (threadIdx.x == 0)
    atomicAdd(out, -(s_sum[0] + s_sum[1] + s_sum[2] + s_sum[3]));
}

// Kernel 2: per-row top-10 + whitelist fixup. One block per row.
__global__ __launch_bounds__(256) void fix_kernel(
    const float* __restrict__ x, const float* __restrict__ y,
    const int* __restrict__ compost, const int* __restrict__ recycle,
    const int* __restrict__ donate, const int* __restrict__ wl_map,
    float* __restrict__ out, const int* __restrict__ cnt,
    const unsigned long long* __restrict__ cand,
    int C, int n1, int n2, int n3, int maxc)
{
  const int row = blockIdx.x;
  const float* xr = x + (size_t)row * (size_t)C;
  const float* yr = y + (size_t)row * (size_t)C;
  const int tid = threadIdx.x;
  const int lane = tid & 63;
  const int wave = tid >> 6;

  __shared__ int s_has[3];
  __shared__ unsigned long long s_top[TOPK];

  if (tid < 3) s_has[tid] = 0;
  __syncthreads();

  // waves 1-3: whitelist presence gathers (benign write-1 races)
  const int ntot = n1 + n2 + n3;
  if (wave > 0) {
    for (int i = tid - 64; i < ntot; i += 192) {
      int which, colI;
      if (i < n1)           { which = 0; colI = compost[i]; }
      else if (i < n1 + n2) { which = 1; colI = recycle[i - n1]; }
      else                  { which = 2; colI = donate[i - n1 - n2]; }
      if (yr[colI] > 0.5f) s_has[which] = 1;
    }
  }

  // wave 0: exact top-10
  if (wave == 0) {
    const int c = cnt[row];
    unsigned long long ls[TOPK];
#pragma unroll
    for (int s = 0; s < TOPK; s++) ls[s] = 0ULL;

#define INSERT(P)                                                          \
    do {                                                                   \
      unsigned long long _p = (P);                                         \
      if (_p > ls[TOPK - 1]) {                                             \
        _Pragma("unroll")                                                  \
        for (int _s = 0; _s < TOPK; _s++) {                                \
          bool _g = _p > ls[_s];                                           \
          unsigned long long _t = _g ? ls[_s] : _p;                        \
          ls[_s] = _g ? _p : ls[_s];                                       \
          _p = _t;                                                         \
        }                                                                  \
      }                                                                    \
    } while (0)

    if (c >= TOPK && c <= maxc) {
      const unsigned long long* cr = cand + (long)row * maxc;
      for (int i = lane; i < c; i += 64) INSERT(cr[i]);
    } else {
      // exact fallback: rescan the (L3-resident) row
      for (int col = lane; col < C; col += 64) INSERT(pack_vc(xr[col], col, C));
    }
#undef INSERT

    // 10 rounds of 64-lane packed max; pop winner (packed values unique)
    for (int r = 0; r < TOPK; r++) {
      unsigned long long mine = ls[0];
      unsigned long long best = mine;
#pragma unroll
      for (int off = 32; off > 0; off >>= 1) {
        unsigned long long o = __shfl_xor(best, off, 64);
        best = (o > best) ? o : best;
      }
      if (lane == 0) s_top[r] = best;
      if (mine == best) {
#pragma unroll
        for (int s = 0; s < TOPK - 1; s++) ls[s] = ls[s + 1];
        ls[TOPK - 1] = 0ULL;
      }
    }
  }
  __syncthreads();

  if (tid == 0) {
    const bool h1 = s_has[0] != 0, h2 = s_has[1] != 0, h3 = s_has[2] != 0;
    const bool gt4 = !(h1 || h2 || h3);

    // rank-sequential multiplier logic (mirrors the lax.scan)
    bool found = false;
    float fr[TOPK];
#pragma unroll
    for (int r = 0; r < TOPK; r++) {
      int col = unpack_c(s_top[r], C);
      int wl = wl_map[col];
      bool in_map = wl > 0;
      bool in_gt = (wl == 1 && h1) || (wl == 2 && h2) ||
                   (wl == 3 && h3) || (wl == 4 && gt4);
      float f = 1.f;
      if (in_map && gt4) f *= ALPHA_OTHER;
      if (in_map && !in_gt && !found) f *= ALPHA1;
      fr[r] = f;
      found = found || (in_map && in_gt);
    }
    const float extra = found ? 1.f : ALPHA1;
    float total = 0.f;
#pragma unroll
    for (int r = 0; r < TOPK; r++) {
      float mult = fr[r] * extra;
      if (mult != 1.f) {
        int col = unpack_c(s_top[r], C);
        float xv = unpack_v(s_top[r]);
        total += (mult - 1.f) * base_w(xv, yr[col] > 0.5f);
      }
    }
    if (total != 0.f) atomicAdd(out, -total);
  }
}

extern "C" void kernel_launch(void* const* d_in, const int* in_sizes, int n_in,
                              void* d_out, int out_size, void* d_ws, size_t ws_size,
                              hipStream_t stream) {
  const float* x       = (const float*)d_in[0];
  const float* y       = (const float*)d_in[1];
  const int*   compost = (const int*)d_in[2];
  const int*   recycle = (const int*)d_in[3];
  const int*   donate  = (const int*)d_in[4];
  const int*   wl_map  = (const int*)d_in[5];
  float* out = (float*)d_out;

  const int C  = in_sizes[5];
  const int B  = in_sizes[0] / C;
  const long N = (long)in_sizes[0];
  const int n1 = in_sizes[2], n2 = in_sizes[3], n3 = in_sizes[4];

  // workspace layout: [0, B*4) row counts; then 8-aligned candidate array
  size_t cand_off = ((size_t)B * 4 + 7) & ~(size_t)7;
  int maxc = MAXC;
  if (ws_size < cand_off + (size_t)B * maxc * 8) {
    size_t fit = (ws_size > cand_off) ? (ws_size - cand_off) / ((size_t)B * 8) : 0;
    maxc = (int)fit;  // maxc < TOPK simply forces the exact fallback path
  }
  int* cnt = (int*)d_ws;
  unsigned long long* cand = (unsigned long long*)((char*)d_ws + cand_off);
  double invC = 1.0 / (double)C;

  // grid sized so each thread handles <= ~12 float4 steps (bitmask fits in 32)
  long N4 = N >> 2;
  long g = (N4 + 256L * 8 - 1) / (256L * 8);
  if (g < 256) g = 256;
  if (g > 16384) g = 16384;

  hipMemsetAsync(out, 0, sizeof(float), stream);
  hipMemsetAsync(cnt, 0, (size_t)B * 4, stream);
  stream_kernel<<<(int)g, 256, 0, stream>>>(x, y, out, cnt, cand, N, C, invC, maxc);
  fix_kernel<<<B, 256, 0, stream>>>(x, y, compost, recycle, donate, wl_map,
                                    out, cnt, cand, C, n1, n2, n3, maxc);
}

// Round 7
// 242.088 us; speedup vs baseline: 1.0185x; 1.0021x over previous
//
#include <hip/hip_runtime.h>

#define TOPK 10
#define CLIP 0.05f
#define EPSV 1e-8f
#define ALPHA1 2.0f
#define ALPHA_OTHER 0.5f
#define TCAND 2.5f     // candidate threshold; guarded by exact fallback in fix_kernel
#define MAXC 128       // per-row candidate capacity (mean ~60, sd ~8 at TCAND=2.5)

#define AS1 __attribute__((address_space(1)))
#define AS3 __attribute__((address_space(3)))

// async global->LDS, 16 B per lane, LDS dest = wave-uniform base + lane*16
__device__ __forceinline__ void gl_lds16(const void* g, void* l) {
  __builtin_amdgcn_global_load_lds((AS1 void*)(size_t)g, (AS3 void*)(size_t)l,
                                   16, 0, 0);
}
// s_waitcnt immediates: vmcnt lo [3:0], expcnt [6:4]=7 (no wait),
// lgkmcnt [11:8]=15 (no wait), vmcnt hi [15:14]=0
#define WAIT_VM2() __builtin_amdgcn_s_waitcnt(0x0F72)   // vmcnt(2)
#define WAIT_VM0() __builtin_amdgcn_s_waitcnt(0x0F70)   // vmcnt(0)

// sortable packed key: (monotone float key << 32) | (C - col)
// larger packed = larger value; on equal value, smaller col wins (matches lax.top_k)
__device__ __forceinline__ unsigned long long pack_vc(float v, int c, int C) {
  unsigned u = __float_as_uint(v);
  unsigned key = (u & 0x80000000u) ? ~u : (u | 0x80000000u);
  return ((unsigned long long)key << 32) | (unsigned)(C - c);
}
__device__ __forceinline__ float unpack_v(unsigned long long p) {
  unsigned key = (unsigned)(p >> 32);
  unsigned u = (key & 0x80000000u) ? (key & 0x7fffffffu) : ~key;
  return __uint_as_float(u);
}
__device__ __forceinline__ int unpack_c(unsigned long long p, int C) {
  return C - (int)(unsigned)(p & 0xffffffffu);
}

// base * w for one element. pos = (y == 1). Fast rcp avoids the full div sequence.
__device__ __forceinline__ float base_w(float xv, bool pos) {
  float e = __expf(-xv);
  float p = __builtin_amdgcn_rcpf(1.f + e);      // sigmoid
  float xneg = fminf(1.f - p + CLIP, 1.f);
  float q = pos ? p : xneg;
  float b = __logf(fmaxf(q, EPSV));
  float t = 1.f - q;                             // 1 - pt
  float t2 = t * t;
  float w = pos ? t : t2 * t2;                   // gamma: pos=1, neg=4
  return b * w;
}

__device__ __forceinline__ void push_cand(float v, long flat, int C, double invC,
                                          int* __restrict__ cnt,
                                          unsigned long long* __restrict__ cand,
                                          int maxc) {
  int row = (int)((double)flat * invC);
  int col = (int)(flat - (long)row * (long)C);
  if (col >= C) { row++; col -= C; }
  if (col < 0)  { row--; col += C; }
  int i = atomicAdd(&cnt[row], 1);
  if (i < maxc) cand[(long)row * maxc + i] = pack_vc(v, col, C);
}

// Kernel 1: flat stream via wave-private 4-deep LDS staging, prefetch 2 ahead,
// explicit s_waitcnt vmcnt(2) at the loop top. No __syncthreads in the loop.
__global__ __launch_bounds__(256) void stream_kernel(
    const float* __restrict__ x, const float* __restrict__ y,
    float* __restrict__ out, int* __restrict__ cnt,
    unsigned long long* __restrict__ cand, long N, int C, double invC, int maxc)
{
  const long N4 = N >> 2;
  const long nstage = N4 >> 6;                 // full 64-float4 stages
  const int lane = threadIdx.x & 63;
  const int wv = threadIdx.x >> 6;
  const long w = (long)blockIdx.x * 4 + wv;    // global wave id
  const long W = (long)gridDim.x * 4;

  const float4* __restrict__ x4 = (const float4*)x;
  const float4* __restrict__ y4 = (const float4*)y;

  // [buf][wave][x/y][lane] : 4*4*2*64*16 = 32 KB
  __shared__ float4 sbuf[4][4][2][64];

  float4 acc = make_float4(0.f, 0.f, 0.f, 0.f);
  unsigned cmask = 0;
  float sum = 0.f;

  const int R = (w < nstage) ? (int)((nstage - w + W - 1) / W) : 0;

  // prologue: prefetch stages 0 and 1 (wave-uniform conditions)
  if (R > 0) {
    gl_lds16(x4 + (w << 6) + lane, &sbuf[0][wv][0][0]);
    gl_lds16(y4 + (w << 6) + lane, &sbuf[0][wv][1][0]);
  }
  if (R > 1) {
    long s1 = w + W;
    gl_lds16(x4 + (s1 << 6) + lane, &sbuf[1][wv][0][0]);
    gl_lds16(y4 + (s1 << 6) + lane, &sbuf[1][wv][1][0]);
  }
  for (int r = 0; r < R; r++) {
    const int b = r & 3;
    // drain exactly this stage's 2 DMA loads; keep the next stage's in flight
    if (r + 2 < R) WAIT_VM2(); else WAIT_VM0();
    float4 X = sbuf[b][wv][0][lane];
    float4 Y = sbuf[b][wv][1][lane];
    if (r + 2 < R) {                            // wave-uniform
      long s2 = w + (long)(r + 2) * W;
      gl_lds16(x4 + (s2 << 6) + lane, &sbuf[(r + 2) & 3][wv][0][0]);
      gl_lds16(y4 + (s2 << 6) + lane, &sbuf[(r + 2) & 3][wv][1][0]);
    }
    acc.x += base_w(X.x, Y.x > 0.5f);
    acc.y += base_w(X.y, Y.y > 0.5f);
    acc.z += base_w(X.z, Y.z > 0.5f);
    acc.w += base_w(X.w, Y.w > 0.5f);
    float mx = fmaxf(fmaxf(X.x, X.y), fmaxf(X.z, X.w));
    cmask |= (mx > TCAND ? 1u : 0u) << r;
  }
  sum = acc.x + acc.y + acc.z + acc.w;

  // materialize candidates (rare; warm-cache reloads, off the hot path)
  while (cmask) {
    int r = __ffs((int)cmask) - 1;
    cmask &= cmask - 1;
    long i4 = ((w + (long)r * W) << 6) + lane;
    float4 X = x4[i4];
    long fb = i4 << 2;
    if (X.x > TCAND) push_cand(X.x, fb + 0, C, invC, cnt, cand, maxc);
    if (X.y > TCAND) push_cand(X.y, fb + 1, C, invC, cnt, cand, maxc);
    if (X.z > TCAND) push_cand(X.z, fb + 2, C, invC, cnt, cand, maxc);
    if (X.w > TCAND) push_cand(X.w, fb + 3, C, invC, cnt, cand, maxc);
  }

  // tail: leftover float4s (N4 % 64) + scalars (N % 4), handled by block 0 wave 0
  if (blockIdx.x == 0 && wv == 0) {
    long base4 = nstage << 6;
    if (base4 + lane < N4) {
      float4 X = x4[base4 + lane];
      float4 Y = y4[base4 + lane];
      long fb = (base4 + lane) << 2;
      sum += base_w(X.x, Y.x > 0.5f) + base_w(X.y, Y.y > 0.5f)
           + base_w(X.z, Y.z > 0.5f) + base_w(X.w, Y.w > 0.5f);
      if (X.x > TCAND) push_cand(X.x, fb + 0, C, invC, cnt, cand, maxc);
      if (X.y > TCAND) push_cand(X.y, fb + 1, C, invC, cnt, cand, maxc);
      if (X.z > TCAND) push_cand(X.z, fb + 2, C, invC, cnt, cand, maxc);
      if (X.w > TCAND) push_cand(X.w, fb + 3, C, invC, cnt, cand, maxc);
    }
    if (lane == 0) {
      for (long j = N4 * 4; j < N; j++) {
        float xv = x[j];
        sum += base_w(xv, y[j] > 0.5f);
        if (xv > TCAND) push_cand(xv, j, C, invC, cnt, cand, maxc);
      }
    }
  }

  // block reduce -> one atomic
#pragma unroll
  for (int off = 32; off > 0; off >>= 1) sum += __shfl_xor(sum, off, 64);
  __shared__ float s_sum[4];
  if (lane == 0) s_sum[wv] = sum;
  __syncthreads();
  if (threadIdx.x == 0)
    atomicAdd(out, -(s_sum[0] + s_sum[1] + s_sum[2] + s_sum[3]));
}

// Kernel 2: per-row top-10 + whitelist fixup. One block per row.
__global__ __launch_bounds__(256) void fix_kernel(
    const float* __restrict__ x, const float* __restrict__ y,
    const int* __restrict__ compost, const int* __restrict__ recycle,
    const int* __restrict__ donate, const int* __restrict__ wl_map,
    float* __restrict__ out, const int* __restrict__ cnt,
    const unsigned long long* __restrict__ cand,
    int C, int n1, int n2, int n3, int maxc)
{
  const int row = blockIdx.x;
  const float* xr = x + (size_t)row * (size_t)C;
  const float* yr = y + (size_t)row * (size_t)C;
  const int tid = threadIdx.x;
  const int lane = tid & 63;
  const int wave = tid >> 6;

  __shared__ int s_has[3];
  __shared__ unsigned long long s_top[TOPK];

  if (tid < 3) s_has[tid] = 0;
  __syncthreads();

  // waves 1-3: whitelist presence gathers (benign write-1 races)
  const int ntot = n1 + n2 + n3;
  if (wave > 0) {
    for (int i = tid - 64; i < ntot; i += 192) {
      int which, colI;
      if (i < n1)           { which = 0; colI = compost[i]; }
      else if (i < n1 + n2) { which = 1; colI = recycle[i - n1]; }
      else                  { which = 2; colI = donate[i - n1 - n2]; }
      if (yr[colI] > 0.5f) s_has[which] = 1;
    }
  }

  // wave 0: exact top-10
  if (wave == 0) {
    const int c = cnt[row];
    unsigned long long ls[TOPK];
#pragma unroll
    for (int s = 0; s < TOPK; s++) ls[s] = 0ULL;

#define INSERT(P)                                                          \
    do {                                                                   \
      unsigned long long _p = (P);                                         \
      if (_p > ls[TOPK - 1]) {                                             \
        _Pragma("unroll")                                                  \
        for (int _s = 0; _s < TOPK; _s++) {                                \
          bool _g = _p > ls[_s];                                           \
          unsigned long long _t = _g ? ls[_s] : _p;                        \
          ls[_s] = _g ? _p : ls[_s];                                       \
          _p = _t;                                                         \
        }                                                                  \
      }                                                                    \
    } while (0)

    if (c >= TOPK && c <= maxc) {
      const unsigned long long* cr = cand + (long)row * maxc;
      for (int i = lane; i < c; i += 64) INSERT(cr[i]);
    } else {
      // exact fallback: rescan the (L3-resident) row
      for (int col = lane; col < C; col += 64) INSERT(pack_vc(xr[col], col, C));
    }
#undef INSERT

    // 10 rounds of 64-lane packed max; pop winner (packed values unique)
    for (int r = 0; r < TOPK; r++) {
      unsigned long long mine = ls[0];
      unsigned long long best = mine;
#pragma unroll
      for (int off = 32; off > 0; off >>= 1) {
        unsigned long long o = __shfl_xor(best, off, 64);
        best = (o > best) ? o : best;
      }
      if (lane == 0) s_top[r] = best;
      if (mine == best) {
#pragma unroll
        for (int s = 0; s < TOPK - 1; s++) ls[s] = ls[s + 1];
        ls[TOPK - 1] = 0ULL;
      }
    }
  }
  __syncthreads();

  if (tid == 0) {
    const bool h1 = s_has[0] != 0, h2 = s_has[1] != 0, h3 = s_has[2] != 0;
    const bool gt4 = !(h1 || h2 || h3);

    // rank-sequential multiplier logic (mirrors the lax.scan)
    bool found = false;
    float fr[TOPK];
#pragma unroll
    for (int r = 0; r < TOPK; r++) {
      int col = unpack_c(s_top[r], C);
      int wl = wl_map[col];
      bool in_map = wl > 0;
      bool in_gt = (wl == 1 && h1) || (wl == 2 && h2) ||
                   (wl == 3 && h3) || (wl == 4 && gt4);
      float f = 1.f;
      if (in_map && gt4) f *= ALPHA_OTHER;
      if (in_map && !in_gt && !found) f *= ALPHA1;
      fr[r] = f;
      found = found || (in_map && in_gt);
    }
    const float extra = found ? 1.f : ALPHA1;
    float total = 0.f;
#pragma unroll
    for (int r = 0; r < TOPK; r++) {
      float mult = fr[r] * extra;
      if (mult != 1.f) {
        int col = unpack_c(s_top[r], C);
        float xv = unpack_v(s_top[r]);
        total += (mult - 1.f) * base_w(xv, yr[col] > 0.5f);
      }
    }
    if (total != 0.f) atomicAdd(out, -total);
  }
}

extern "C" void kernel_launch(void* const* d_in, const int* in_sizes, int n_in,
                              void* d_out, int out_size, void* d_ws, size_t ws_size,
                              hipStream_t stream) {
  const float* x       = (const float*)d_in[0];
  const float* y       = (const float*)d_in[1];
  const int*   compost = (const int*)d_in[2];
  const int*   recycle = (const int*)d_in[3];
  const int*   donate  = (const int*)d_in[4];
  const int*   wl_map  = (const int*)d_in[5];
  float* out = (float*)d_out;

  const int C  = in_sizes[5];
  const int B  = in_sizes[0] / C;
  const long N = (long)in_sizes[0];
  const int n1 = in_sizes[2], n2 = in_sizes[3], n3 = in_sizes[4];

  // workspace layout: [0, B*4) row counts; then 8-aligned candidate array
  size_t cand_off = ((size_t)B * 4 + 7) & ~(size_t)7;
  int maxc = MAXC;
  if (ws_size < cand_off + (size_t)B * maxc * 8) {
    size_t fit = (ws_size > cand_off) ? (ws_size - cand_off) / ((size_t)B * 8) : 0;
    maxc = (int)fit;  // maxc < TOPK simply forces the exact fallback path
  }
  int* cnt = (int*)d_ws;
  unsigned long long* cand = (unsigned long long*)((char*)d_ws + cand_off);
  double invC = 1.0 / (double)C;

  hipMemsetAsync(out, 0, sizeof(float), stream);
  hipMemsetAsync(cnt, 0, (size_t)B * 4, stream);
  // 1280 blocks = 5 blocks/CU (32 KB LDS each), R <= 16 stages/wave
  stream_kernel<<<1280, 256, 0, stream>>>(x, y, out, cnt, cand, N, C, invC, maxc);
  fix_kernel<<<B, 256, 0, stream>>>(x, y, compost, recycle, donate, wl_map,
                                    out, cnt, cand, C, n1, n2, n3, maxc);
}